// Round 10
// baseline (40.503 us; speedup 1.0000x reference)
//
#include <hip/hip_runtime.h>
#include <math.h>

#define LN_EPS 1e-5f

typedef _Float16 f16;
typedef _Float16 f16x8 __attribute__((ext_vector_type(8)));
typedef _Float16 f16x2 __attribute__((ext_vector_type(2)));
typedef float f32x4 __attribute__((ext_vector_type(4)));

constexpr int DC = 16;
constexpr int K = 8192;
constexpr int NTOK = 16384;        // 8*2048
constexpr int D = 512;
constexpr float SCALE = 16384.f;   // 256 * 64, exact powers of 2
constexpr float EPS_S = LN_EPS * SCALE * SCALE;

static __device__ __forceinline__ f16x8 mk8(f16x2 a, f16x2 b, f16x2 c,
                                            f16x2 d) {
  union {
    f16x2 p[4];
    f16x8 v;
  } u;
  u.p[0] = a;
  u.p[1] = b;
  u.p[2] = c;
  u.p[3] = d;
  return u.v;
}

// hi = f32 masked to 11-bit mantissa (exact in f16; pkrtz exact on it),
// lo = residual (err <= 2^-23 * |v| total).
static __device__ __forceinline__ void hilo2(float f0, float f1, f16x2& ph,
                                             f16x2& pl) {
  float h0 = __uint_as_float(__float_as_uint(f0) & 0xFFFFE000u);
  float h1 = __uint_as_float(__float_as_uint(f1) & 0xFFFFE000u);
  ph = __builtin_bit_cast(f16x2, __builtin_amdgcn_cvt_pkrtz(h0, h1));
  pl = __builtin_bit_cast(f16x2,
                          __builtin_amdgcn_cvt_pkrtz(f0 - h0, f1 - h1));
}

// ---------------------------------------------------------------------------
// prep: blocks [0,128): codebook -> cbA A-frags (x -128, hi/lo) + biased c2.
//       block 128: W -> wAf A-frags (x 64, hi/lo), 32 tiles.
// Frag per 16-row tile: lane l holds 8 halves, slots s=(l>>4)*8+p;
// s<16 -> hi(dim s), s>=16 -> lo(dim s-16). Rows = l&15.
// ---------------------------------------------------------------------------
__global__ __launch_bounds__(256) void prep(const float* __restrict__ cb,
                                            const float* __restrict__ wq,
                                            f16* __restrict__ cbA,
                                            float* __restrict__ c2s,
                                            f16* __restrict__ wAf) {
  const int tid = threadIdx.x;

  if (blockIdx.x == K / 64) {
#pragma unroll
    for (int i = 0; i < 8; ++i) {
      int slot = tid + 256 * i;
      int tile = slot >> 6;
      int l = slot & 63;
      int g = l >> 4;
      int col = l & 15;
      int doff = (g & 1) * 8;
      const float* wp = wq + (size_t)col * D + tile * 16 + doff;
      f32x4 u0 = *(const f32x4*)wp;
      f32x4 u1 = *(const f32x4*)(wp + 4);
      f16x2 ph[4], pl[4];
      hilo2(u0[0] * 64.f, u0[1] * 64.f, ph[0], pl[0]);
      hilo2(u0[2] * 64.f, u0[3] * 64.f, ph[1], pl[1]);
      hilo2(u1[0] * 64.f, u1[1] * 64.f, ph[2], pl[2]);
      hilo2(u1[2] * 64.f, u1[3] * 64.f, ph[3], pl[3]);
      f16x8 hi = mk8(ph[0], ph[1], ph[2], ph[3]);
      f16x8 lo = mk8(pl[0], pl[1], pl[2], pl[3]);
      *(f16x8*)(wAf + (size_t)slot * 8) = (g < 2) ? hi : lo;
    }
    return;
  }

  const int ti = tid >> 6;
  const int l = tid & 63;
  const int ct = blockIdx.x * 4 + ti;
  const int code = ct * 16 + (l & 15);
  const int g = l >> 4;

  const float* row = cb + (size_t)code * DC + (g & 1) * 8;
  f32x4 v0 = *(const f32x4*)row;
  f32x4 v1 = *(const f32x4*)(row + 4);
  f16x2 ph[4], pl[4];
  hilo2(v0[0] * -128.f, v0[1] * -128.f, ph[0], pl[0]);
  hilo2(v0[2] * -128.f, v0[3] * -128.f, ph[1], pl[1]);
  hilo2(v1[0] * -128.f, v1[1] * -128.f, ph[2], pl[2]);
  hilo2(v1[2] * -128.f, v1[3] * -128.f, ph[3], pl[3]);
  f16x8 hi = mk8(ph[0], ph[1], ph[2], ph[3]);
  f16x8 lo = mk8(pl[0], pl[1], pl[2], pl[3]);
  *(f16x8*)(cbA + ((size_t)ct * 64 + l) * 8) = (g < 2) ? hi : lo;

  if (g == 0) {
    const f32x4* rw = (const f32x4*)(cb + (size_t)code * DC);
    f32x4 a0 = rw[0], a1 = rw[1], a2 = rw[2], a3 = rw[3];
    float s = 0.f;
#pragma unroll
    for (int p = 0; p < 4; ++p)
      s += a0[p] * a0[p] + a1[p] * a1[p] + a2[p] * a2[p] + a3[p] * a3[p];
    c2s[code] = (s + 16.5f) * SCALE;   // +16.5 > h2=16 keeps dist > 0
  }
}

// ---------------------------------------------------------------------------
// fused: 512 blocks x 1024 thr, __launch_bounds__(1024,8) -> 2 blocks/CU =
// 8 waves/SIMD (hardware max TLP; the round-9 structure idled pipes ~70% on
// load latency at 4 waves/SIMD). Block owns 32 tokens (2 tiles).
// Phase A: wave (j=w&1 tile, dq8=w>>1 D-eighth, 4 K-steps): x direct from
//   global, W frags preloaded, 8 MFMA -> partial C; combine 8 partials via
//   LDS; LN width-16 shfl (scaled, EPS_S).
// Phase B: wave w sweeps its 512-code slice (32 tiles) for both token-tiles;
//   tag-free running min + per-8-iter group tag; setprio around the MFMA
//   cluster (wave-diverse phases -> scheduler has something to arbitrate).
// Merge 16 wave-candidates; winning 32-code group disambiguated by exact
// fp32 recompute (16 threads/token). Straight to d_out.
// ---------------------------------------------------------------------------
__global__ __launch_bounds__(1024, 8) void fused(
    const float* __restrict__ x, const float* __restrict__ cb,
    const f16* __restrict__ cbA, const float* __restrict__ c2s,
    const f16* __restrict__ wAf, int* __restrict__ out) {
  __shared__ float comb[16 * 16 * 20];  // 20.5 KB [w][col][20]
  __shared__ float hsm[32 * 20];        // 2.6 KB  [tok][20]
  __shared__ float fin_d[16][32];       // 2 KB
  __shared__ int fin_t[16][32];         // 2 KB

  const int tid = threadIdx.x;
  const int w = tid >> 6;
  const int lane = tid & 63;
  const int g = lane >> 4;
  const int col = lane & 15;
  const int doff = (g & 1) * 8;
  const int tb = blockIdx.x * 32;

  // ---------------- phase A: this wave = (tile j, D-eighth dq8) -----------
  const int j = w & 1;
  const int dq8 = w >> 1;

  const float* xrow = x + (size_t)(tb + j * 16 + col) * D + dq8 * 64 + doff;
  f32x4 xu0[4], xu1[4];
#pragma unroll
  for (int st = 0; st < 4; ++st) {
    xu0[st] = *(const f32x4*)(xrow + st * 16);
    xu1[st] = *(const f32x4*)(xrow + st * 16 + 4);
  }
  f16x8 aw[4];
#pragma unroll
  for (int st = 0; st < 4; ++st)
    aw[st] = *(const f16x8*)(wAf + ((size_t)(dq8 * 4 + st) * 64 + lane) * 8);

  f32x4 acc = {0.f, 0.f, 0.f, 0.f};
#pragma unroll
  for (int st = 0; st < 4; ++st) {
    f16x2 ph[4], pl[4];
    hilo2(xu0[st][0] * 256.f, xu0[st][1] * 256.f, ph[0], pl[0]);
    hilo2(xu0[st][2] * 256.f, xu0[st][3] * 256.f, ph[1], pl[1]);
    hilo2(xu1[st][0] * 256.f, xu1[st][1] * 256.f, ph[2], pl[2]);
    hilo2(xu1[st][2] * 256.f, xu1[st][3] * 256.f, ph[3], pl[3]);
    f16x8 bh = mk8(ph[0], ph[1], ph[2], ph[3]);
    f16x8 bl = mk8(pl[0], pl[1], pl[2], pl[3]);
    f16x8 b1 = (g < 2) ? bh : bl;
    f16x8 b2 = (g < 2) ? bl : bh;
    acc = __builtin_amdgcn_mfma_f32_16x16x32_f16(aw[st], b1, acc, 0, 0, 0);
    acc = __builtin_amdgcn_mfma_f32_16x16x32_f16(aw[st], b2, acc, 0, 0, 0);
  }
  *(f32x4*)&comb[(w * 16 + col) * 20 + g * 4] = acc;
  __syncthreads();

  // ---------------- LayerNorm (scaled values; exact ratio) ----------------
  if (tid < 512) {
    const int tokL = tid >> 4;         // 0..31
    const int cL = tid & 15;
    const int jL = tokL >> 4;
    const int colL = tokL & 15;
    float hv = 0.f;
#pragma unroll
    for (int dq = 0; dq < 8; ++dq)
      hv += comb[((dq * 2 + jL) * 16 + colL) * 20 + cL];
    float s = hv;
    s += __shfl_xor(s, 1, 16);
    s += __shfl_xor(s, 2, 16);
    s += __shfl_xor(s, 4, 16);
    s += __shfl_xor(s, 8, 16);
    float mu = s * (1.f / 16.f);
    float diff = hv - mu;
    float v2 = diff * diff;
    v2 += __shfl_xor(v2, 1, 16);
    v2 += __shfl_xor(v2, 2, 16);
    v2 += __shfl_xor(v2, 4, 16);
    v2 += __shfl_xor(v2, 8, 16);
    float var = v2 * (1.f / 16.f);
    hsm[tokL * 20 + cL] = diff / sqrtf(var + EPS_S);  // unscaled LN'd h
  }
  __syncthreads();

  // ---------------- phase B: B frags for the 2 token-tiles ----------------
  f16x8 b1[2], b2[2];
#pragma unroll
  for (int jj = 0; jj < 2; ++jj) {
    const float* hp = &hsm[(jj * 16 + col) * 20 + doff];
    f32x4 u0 = *(const f32x4*)hp;
    f32x4 u1 = *(const f32x4*)(hp + 4);
    f16x2 ph[4], pl[4];
    hilo2(u0[0] * 256.f, u0[1] * 256.f, ph[0], pl[0]);
    hilo2(u0[2] * 256.f, u0[3] * 256.f, ph[1], pl[1]);
    hilo2(u1[0] * 256.f, u1[1] * 256.f, ph[2], pl[2]);
    hilo2(u1[2] * 256.f, u1[3] * 256.f, ph[3], pl[3]);
    f16x8 bh = mk8(ph[0], ph[1], ph[2], ph[3]);
    f16x8 bl = mk8(pl[0], pl[1], pl[2], pl[3]);
    b1[jj] = (g < 2) ? bh : bl;
    b2[jj] = (g < 2) ? bl : bh;
  }

  // ---------------- phase B sweep: 32 tiles, tag-free min ----------------
  const int q = w;                     // slice [q*512, (q+1)*512)
  float best0 = 3.0e38f, best1 = 3.0e38f;
  int grp0 = 0, grp1 = 0;
  const f16* pa = cbA + ((size_t)q * 32 * 64 + lane) * 8;
  const float* pc = c2s + q * 512 + g * 4;

  for (int gi = 0; gi < 4; ++gi) {
    float sb0 = best0, sb1 = best1;
#pragma unroll
    for (int ti = 0; ti < 8; ++ti) {
      int t = gi * 8 + ti;
      f16x8 a = *(const f16x8*)(pa + (size_t)t * 512);
      f32x4 c2v = *(const f32x4*)(pc + t * 16);
      __builtin_amdgcn_s_setprio(1);
      f32x4 a0 = __builtin_amdgcn_mfma_f32_16x16x32_f16(a, b1[0], c2v, 0, 0, 0);
      a0 = __builtin_amdgcn_mfma_f32_16x16x32_f16(a, b2[0], a0, 0, 0, 0);
      f32x4 a1 = __builtin_amdgcn_mfma_f32_16x16x32_f16(a, b1[1], c2v, 0, 0, 0);
      a1 = __builtin_amdgcn_mfma_f32_16x16x32_f16(a, b2[1], a1, 0, 0, 0);
      __builtin_amdgcn_s_setprio(0);
      best0 = fminf(best0, fminf(fminf(a0[0], a0[1]), fminf(a0[2], a0[3])));
      best1 = fminf(best1, fminf(fminf(a1[0], a1[1]), fminf(a1[2], a1[3])));
    }
    grp0 = (best0 < sb0) ? gi : grp0;  // strict <: earliest group on ties
    grp1 = (best1 < sb1) ? gi : grp1;
  }

  // merge lane-groups per tile; tag = grp*4+g (grp major == k major)
  int tg0 = grp0 * 4 + g, tg1 = grp1 * 4 + g;
#pragma unroll
  for (int off = 16; off <= 32; off <<= 1) {
    float od = __shfl_xor(best0, off);
    int ot = __shfl_xor(tg0, off);
    bool tk = (od < best0) || (od == best0 && ot < tg0);
    best0 = tk ? od : best0;
    tg0 = tk ? ot : tg0;
    od = __shfl_xor(best1, off);
    ot = __shfl_xor(tg1, off);
    tk = (od < best1) || (od == best1 && ot < tg1);
    best1 = tk ? od : best1;
    tg1 = tk ? ot : tg1;
  }
  if (lane < 16) {
    fin_d[q][lane] = best0;
    fin_t[q][lane] = tg0;
    fin_d[q][16 + lane] = best1;
    fin_t[q][16 + lane] = tg1;
  }
  __syncthreads();

  // ---------------- finalize: 16 threads/token, 32-code exact verify ------
  if (tid < 512) {
    const int tok = tid >> 4;
    const int c = tid & 15;
    float bd = fin_d[0][tok];
    int btag = fin_t[0][tok];
    int bq = 0;
#pragma unroll
    for (int q2 = 1; q2 < 16; ++q2) {
      float d2 = fin_d[q2][tok];
      int t2 = fin_t[q2][tok];
      bool tk = d2 < bd;               // ascending q: strict <
      bd = tk ? d2 : bd;
      btag = tk ? t2 : btag;
      bq = tk ? q2 : bq;
    }
    const int kb = bq * 512 + (btag >> 2) * 128 + (btag & 3) * 4;

    f32x4 h0 = *(const f32x4*)&hsm[tok * 20];
    f32x4 h1 = *(const f32x4*)&hsm[tok * 20 + 4];
    f32x4 h2 = *(const f32x4*)&hsm[tok * 20 + 8];
    f32x4 h3 = *(const f32x4*)&hsm[tok * 20 + 12];

    float bestd = 3.0e38f;
    int bestk = kb;
#pragma unroll
    for (int e2 = 0; e2 < 2; ++e2) {
      int e = c * 2 + e2;              // e ascending == k ascending
      int kk = kb + (e >> 2) * 16 + (e & 3);
      const f32x4* cr = (const f32x4*)(cb + (size_t)kk * DC);
      f32x4 c0 = cr[0], c1 = cr[1], c2r = cr[2], c3 = cr[3];
      float sd = 0.f;
#pragma unroll
      for (int p = 0; p < 4; ++p) {
        float d0 = h0[p] - c0[p];
        float d1 = h1[p] - c1[p];
        float dd2 = h2[p] - c2r[p];
        float d3 = h3[p] - c3[p];
        sd = fmaf(d0, d0, sd);
        sd = fmaf(d1, d1, sd);
        sd = fmaf(dd2, dd2, sd);
        sd = fmaf(d3, d3, sd);
      }
      bool tk = sd < bestd;
      bestd = tk ? sd : bestd;
      bestk = tk ? kk : bestk;
    }
#pragma unroll
    for (int off = 1; off < 16; off <<= 1) {
      float od = __shfl_xor(bestd, off, 16);
      int ok = __shfl_xor(bestk, off, 16);
      bool tk = (od < bestd) || (od == bestd && ok < bestk);
      bestd = tk ? od : bestd;
      bestk = tk ? ok : bestk;
    }
    if (c == 0) out[tb + tok] = bestk;
  }
}

// ---------------------------------------------------------------------------
extern "C" void kernel_launch(void* const* d_in, const int* in_sizes, int n_in,
                              void* d_out, int out_size, void* d_ws,
                              size_t ws_size, hipStream_t stream) {
  const float* x = (const float*)d_in[0];    // (8,2048,512)
  const float* w = (const float*)d_in[1];    // (16,512)
  const float* cb = (const float*)d_in[2];   // (8192,16)

  f16* cbA = (f16*)d_ws;                        // 512 KB
  float* c2s = (float*)(cbA + (size_t)K * 32);  // 32 KB
  f16* wAf = (f16*)(c2s + K);                   // 32 KB

  prep<<<K / 64 + 1, 256, 0, stream>>>(cb, w, cbA, c2s, wAf);
  fused<<<NTOK / 32, 1024, 0, stream>>>(x, cb, cbA, c2s, wAf, (int*)d_out);
}

// Round 11
// 39.581 us; speedup vs baseline: 1.0233x; 1.0233x over previous
//
#include <hip/hip_runtime.h>
#include <math.h>

#define LN_EPS 1e-5f

typedef _Float16 f16;
typedef _Float16 f16x8 __attribute__((ext_vector_type(8)));
typedef _Float16 f16x2 __attribute__((ext_vector_type(2)));
typedef float f32x4 __attribute__((ext_vector_type(4)));

constexpr int DC = 16;
constexpr int K = 8192;
constexpr int NTOK = 16384;        // 8*2048
constexpr int D = 512;
constexpr float SCALE = 16384.f;   // 256 * 64, exact powers of 2
constexpr float EPS_S = LN_EPS * SCALE * SCALE;

static __device__ __forceinline__ f16x8 mk8(f16x2 a, f16x2 b, f16x2 c,
                                            f16x2 d) {
  union {
    f16x2 p[4];
    f16x8 v;
  } u;
  u.p[0] = a;
  u.p[1] = b;
  u.p[2] = c;
  u.p[3] = d;
  return u.v;
}

// hi = f32 masked to 11-bit mantissa (exact in f16; pkrtz exact on it),
// lo = residual (err <= 2^-23 * |v| total).
static __device__ __forceinline__ void hilo2(float f0, float f1, f16x2& ph,
                                             f16x2& pl) {
  float h0 = __uint_as_float(__float_as_uint(f0) & 0xFFFFE000u);
  float h1 = __uint_as_float(__float_as_uint(f1) & 0xFFFFE000u);
  ph = __builtin_bit_cast(f16x2, __builtin_amdgcn_cvt_pkrtz(h0, h1));
  pl = __builtin_bit_cast(f16x2,
                          __builtin_amdgcn_cvt_pkrtz(f0 - h0, f1 - h1));
}

// ---------------------------------------------------------------------------
// prep: blocks [0,128): codebook -> cbA A-frags (x -128, hi/lo) + biased c2.
//       block 128: W -> wAf A-frags (x 64, hi/lo), 32 tiles.
// Frag per 16-row tile: lane l holds 8 halves, slots s=(l>>4)*8+p;
// s<16 -> hi(dim s), s>=16 -> lo(dim s-16). Rows = l&15.
// ---------------------------------------------------------------------------
__global__ __launch_bounds__(256) void prep(const float* __restrict__ cb,
                                            const float* __restrict__ wq,
                                            f16* __restrict__ cbA,
                                            float* __restrict__ c2s,
                                            f16* __restrict__ wAf) {
  const int tid = threadIdx.x;

  if (blockIdx.x == K / 64) {
#pragma unroll
    for (int i = 0; i < 8; ++i) {
      int slot = tid + 256 * i;
      int tile = slot >> 6;
      int l = slot & 63;
      int g = l >> 4;
      int col = l & 15;
      int doff = (g & 1) * 8;
      const float* wp = wq + (size_t)col * D + tile * 16 + doff;
      f32x4 u0 = *(const f32x4*)wp;
      f32x4 u1 = *(const f32x4*)(wp + 4);
      f16x2 ph[4], pl[4];
      hilo2(u0[0] * 64.f, u0[1] * 64.f, ph[0], pl[0]);
      hilo2(u0[2] * 64.f, u0[3] * 64.f, ph[1], pl[1]);
      hilo2(u1[0] * 64.f, u1[1] * 64.f, ph[2], pl[2]);
      hilo2(u1[2] * 64.f, u1[3] * 64.f, ph[3], pl[3]);
      f16x8 hi = mk8(ph[0], ph[1], ph[2], ph[3]);
      f16x8 lo = mk8(pl[0], pl[1], pl[2], pl[3]);
      *(f16x8*)(wAf + (size_t)slot * 8) = (g < 2) ? hi : lo;
    }
    return;
  }

  const int ti = tid >> 6;
  const int l = tid & 63;
  const int ct = blockIdx.x * 4 + ti;
  const int code = ct * 16 + (l & 15);
  const int g = l >> 4;

  const float* row = cb + (size_t)code * DC + (g & 1) * 8;
  f32x4 v0 = *(const f32x4*)row;
  f32x4 v1 = *(const f32x4*)(row + 4);
  f16x2 ph[4], pl[4];
  hilo2(v0[0] * -128.f, v0[1] * -128.f, ph[0], pl[0]);
  hilo2(v0[2] * -128.f, v0[3] * -128.f, ph[1], pl[1]);
  hilo2(v1[0] * -128.f, v1[1] * -128.f, ph[2], pl[2]);
  hilo2(v1[2] * -128.f, v1[3] * -128.f, ph[3], pl[3]);
  f16x8 hi = mk8(ph[0], ph[1], ph[2], ph[3]);
  f16x8 lo = mk8(pl[0], pl[1], pl[2], pl[3]);
  *(f16x8*)(cbA + ((size_t)ct * 64 + l) * 8) = (g < 2) ? hi : lo;

  if (g == 0) {
    const f32x4* rw = (const f32x4*)(cb + (size_t)code * DC);
    f32x4 a0 = rw[0], a1 = rw[1], a2 = rw[2], a3 = rw[3];
    float s = 0.f;
#pragma unroll
    for (int p = 0; p < 4; ++p)
      s += a0[p] * a0[p] + a1[p] * a1[p] + a2[p] * a2[p] + a3[p] * a3[p];
    c2s[code] = (s + 16.5f) * SCALE;   // +16.5 > h2=16 keeps dist > 0
  }
}

// ---------------------------------------------------------------------------
// fused: 256 blocks x 1024 thr, __launch_bounds__(1024,4) (VGPR cap 128 —
// round-10's (1024,8) forced a 64-reg budget that likely spilled/was ignored).
// Block owns 64 tokens -> cbA traffic HALVES (134 MB total) and phase B does
// 8 MFMA per 2 loads (4x the MFMA:VMEM ratio of round 10).
// Phase A: wave (j=w&3 tile, dq=w>>2 D-quarter, 8 K-steps): x direct from
//   global, W frags preloaded; combine 4 partials via LDS; LN width-16 shfl.
// Phase B: wave w sweeps its 512-code slice (32 tiles) for 4 token-tiles;
//   tag-free running min + per-8-tile group tag; setprio around MFMA cluster.
// Merge 16 wave-candidates; winning 32-code group disambiguated by exact
// fp32 recompute (16 threads/token). Straight to d_out.
// ---------------------------------------------------------------------------
__global__ __launch_bounds__(1024, 4) void fused(
    const float* __restrict__ x, const float* __restrict__ cb,
    const f16* __restrict__ cbA, const float* __restrict__ c2s,
    const f16* __restrict__ wAf, int* __restrict__ out) {
  __shared__ float comb[16 * 16 * 20];  // 20.5 KB [w][col][20]
  __shared__ float hsm[64 * 20];        // 5.1 KB  [tok][20]
  __shared__ float fin_d[16][64];       // 4 KB
  __shared__ int fin_t[16][64];         // 4 KB

  const int tid = threadIdx.x;
  const int w = tid >> 6;
  const int lane = tid & 63;
  const int g = lane >> 4;
  const int col = lane & 15;
  const int doff = (g & 1) * 8;
  const int tb = blockIdx.x * 64;

  // ---------------- phase A: wave = (tile j, D-quarter dq) ----------------
  const int j = w & 3;
  const int dq = w >> 2;

  const float* xrow = x + (size_t)(tb + j * 16 + col) * D + dq * 128 + doff;
  f32x4 acc = {0.f, 0.f, 0.f, 0.f};
#pragma unroll
  for (int st = 0; st < 8; ++st) {
    f16x8 aw =
        *(const f16x8*)(wAf + ((size_t)(dq * 8 + st) * 64 + lane) * 8);
    f32x4 u0 = *(const f32x4*)(xrow + st * 16);
    f32x4 u1 = *(const f32x4*)(xrow + st * 16 + 4);
    f16x2 ph[4], pl[4];
    hilo2(u0[0] * 256.f, u0[1] * 256.f, ph[0], pl[0]);
    hilo2(u0[2] * 256.f, u0[3] * 256.f, ph[1], pl[1]);
    hilo2(u1[0] * 256.f, u1[1] * 256.f, ph[2], pl[2]);
    hilo2(u1[2] * 256.f, u1[3] * 256.f, ph[3], pl[3]);
    f16x8 bh = mk8(ph[0], ph[1], ph[2], ph[3]);
    f16x8 bl = mk8(pl[0], pl[1], pl[2], pl[3]);
    f16x8 b1 = (g < 2) ? bh : bl;
    f16x8 b2 = (g < 2) ? bl : bh;
    acc = __builtin_amdgcn_mfma_f32_16x16x32_f16(aw, b1, acc, 0, 0, 0);
    acc = __builtin_amdgcn_mfma_f32_16x16x32_f16(aw, b2, acc, 0, 0, 0);
  }
  *(f32x4*)&comb[(w * 16 + col) * 20 + g * 4] = acc;
  __syncthreads();

  // ---------------- LayerNorm (scaled values; exact ratio) ----------------
  {
    const int tokL = tid >> 4;           // 0..63
    const int cL = tid & 15;
    const int jL = tokL >> 4;            // tile
    const int colL = tokL & 15;
    float hv = 0.f;
#pragma unroll
    for (int dq2 = 0; dq2 < 4; ++dq2)
      hv += comb[((dq2 * 4 + jL) * 16 + colL) * 20 + cL];
    float s = hv;
    s += __shfl_xor(s, 1, 16);
    s += __shfl_xor(s, 2, 16);
    s += __shfl_xor(s, 4, 16);
    s += __shfl_xor(s, 8, 16);
    float mu = s * (1.f / 16.f);
    float diff = hv - mu;
    float v2 = diff * diff;
    v2 += __shfl_xor(v2, 1, 16);
    v2 += __shfl_xor(v2, 2, 16);
    v2 += __shfl_xor(v2, 4, 16);
    v2 += __shfl_xor(v2, 8, 16);
    float var = v2 * (1.f / 16.f);
    hsm[tokL * 20 + cL] = diff / sqrtf(var + EPS_S);  // unscaled LN'd h
  }
  __syncthreads();

  // ---------------- phase B: B frags for the 4 token-tiles ----------------
  f16x8 b1[4], b2[4];
#pragma unroll
  for (int jj = 0; jj < 4; ++jj) {
    const float* hp = &hsm[(jj * 16 + col) * 20 + doff];
    f32x4 u0 = *(const f32x4*)hp;
    f32x4 u1 = *(const f32x4*)(hp + 4);
    f16x2 ph[4], pl[4];
    hilo2(u0[0] * 256.f, u0[1] * 256.f, ph[0], pl[0]);
    hilo2(u0[2] * 256.f, u0[3] * 256.f, ph[1], pl[1]);
    hilo2(u1[0] * 256.f, u1[1] * 256.f, ph[2], pl[2]);
    hilo2(u1[2] * 256.f, u1[3] * 256.f, ph[3], pl[3]);
    f16x8 bh = mk8(ph[0], ph[1], ph[2], ph[3]);
    f16x8 bl = mk8(pl[0], pl[1], pl[2], pl[3]);
    b1[jj] = (g < 2) ? bh : bl;
    b2[jj] = (g < 2) ? bl : bh;
  }

  // ---------------- phase B sweep: 32 tiles, JT=4, tag-free min -----------
  const int q = w;                       // slice [q*512, (q+1)*512)
  float best[4] = {3.0e38f, 3.0e38f, 3.0e38f, 3.0e38f};
  int grp[4] = {0, 0, 0, 0};
  const f16* pa = cbA + ((size_t)q * 32 * 64 + lane) * 8;
  const float* pc = c2s + q * 512 + g * 4;

  for (int gi = 0; gi < 4; ++gi) {
    float sb0 = best[0], sb1 = best[1], sb2 = best[2], sb3 = best[3];
#pragma unroll
    for (int ti = 0; ti < 8; ++ti) {
      int t = gi * 8 + ti;
      f16x8 a = *(const f16x8*)(pa + (size_t)t * 512);
      f32x4 c2v = *(const f32x4*)(pc + t * 16);
      __builtin_amdgcn_s_setprio(1);
      f32x4 d0 = __builtin_amdgcn_mfma_f32_16x16x32_f16(a, b1[0], c2v, 0, 0, 0);
      d0 = __builtin_amdgcn_mfma_f32_16x16x32_f16(a, b2[0], d0, 0, 0, 0);
      f32x4 d1 = __builtin_amdgcn_mfma_f32_16x16x32_f16(a, b1[1], c2v, 0, 0, 0);
      d1 = __builtin_amdgcn_mfma_f32_16x16x32_f16(a, b2[1], d1, 0, 0, 0);
      f32x4 d2 = __builtin_amdgcn_mfma_f32_16x16x32_f16(a, b1[2], c2v, 0, 0, 0);
      d2 = __builtin_amdgcn_mfma_f32_16x16x32_f16(a, b2[2], d2, 0, 0, 0);
      f32x4 d3 = __builtin_amdgcn_mfma_f32_16x16x32_f16(a, b1[3], c2v, 0, 0, 0);
      d3 = __builtin_amdgcn_mfma_f32_16x16x32_f16(a, b2[3], d3, 0, 0, 0);
      __builtin_amdgcn_s_setprio(0);
      best[0] = fminf(best[0], fminf(fminf(d0[0], d0[1]), fminf(d0[2], d0[3])));
      best[1] = fminf(best[1], fminf(fminf(d1[0], d1[1]), fminf(d1[2], d1[3])));
      best[2] = fminf(best[2], fminf(fminf(d2[0], d2[1]), fminf(d2[2], d2[3])));
      best[3] = fminf(best[3], fminf(fminf(d3[0], d3[1]), fminf(d3[2], d3[3])));
    }
    grp[0] = (best[0] < sb0) ? gi : grp[0];  // strict <: earliest group wins
    grp[1] = (best[1] < sb1) ? gi : grp[1];
    grp[2] = (best[2] < sb2) ? gi : grp[2];
    grp[3] = (best[3] < sb3) ? gi : grp[3];
  }

  // merge lane-groups per token-tile; tag = grp*4+g (grp major == k major)
#pragma unroll
  for (int jj = 0; jj < 4; ++jj) {
    float d = best[jj];
    int tg = grp[jj] * 4 + g;
#pragma unroll
    for (int off = 16; off <= 32; off <<= 1) {
      float od = __shfl_xor(d, off);
      int ot = __shfl_xor(tg, off);
      bool tk = (od < d) || (od == d && ot < tg);
      d = tk ? od : d;
      tg = tk ? ot : tg;
    }
    if (lane < 16) {
      fin_d[q][jj * 16 + lane] = d;
      fin_t[q][jj * 16 + lane] = tg;
    }
  }
  __syncthreads();

  // ---------------- finalize: 16 threads/token, 32-code exact verify ------
  {
    const int tok = tid >> 4;            // 0..63
    const int c = tid & 15;
    float bd = fin_d[0][tok];
    int btag = fin_t[0][tok];
    int bq = 0;
#pragma unroll
    for (int q2 = 1; q2 < 16; ++q2) {
      float d2 = fin_d[q2][tok];
      int t2 = fin_t[q2][tok];
      bool tk = d2 < bd;                 // ascending q: strict <
      bd = tk ? d2 : bd;
      btag = tk ? t2 : btag;
      bq = tk ? q2 : bq;
    }
    const int kb = bq * 512 + (btag >> 2) * 128 + (btag & 3) * 4;

    f32x4 h0 = *(const f32x4*)&hsm[tok * 20];
    f32x4 h1 = *(const f32x4*)&hsm[tok * 20 + 4];
    f32x4 h2 = *(const f32x4*)&hsm[tok * 20 + 8];
    f32x4 h3 = *(const f32x4*)&hsm[tok * 20 + 12];

    float bestd = 3.0e38f;
    int bestk = kb;
#pragma unroll
    for (int e2 = 0; e2 < 2; ++e2) {
      int e = c * 2 + e2;                // e ascending == k ascending
      int kk = kb + (e >> 2) * 16 + (e & 3);
      const f32x4* cr = (const f32x4*)(cb + (size_t)kk * DC);
      f32x4 c0 = cr[0], c1 = cr[1], c2r = cr[2], c3 = cr[3];
      float sd = 0.f;
#pragma unroll
      for (int p = 0; p < 4; ++p) {
        float e0 = h0[p] - c0[p];
        float e1 = h1[p] - c1[p];
        float e2f = h2[p] - c2r[p];
        float e3 = h3[p] - c3[p];
        sd = fmaf(e0, e0, sd);
        sd = fmaf(e1, e1, sd);
        sd = fmaf(e2f, e2f, sd);
        sd = fmaf(e3, e3, sd);
      }
      bool tk = sd < bestd;
      bestd = tk ? sd : bestd;
      bestk = tk ? kk : bestk;
    }
#pragma unroll
    for (int off = 1; off < 16; off <<= 1) {
      float od = __shfl_xor(bestd, off, 16);
      int ok = __shfl_xor(bestk, off, 16);
      bool tk = (od < bestd) || (od == bestd && ok < bestk);
      bestd = tk ? od : bestd;
      bestk = tk ? ok : bestk;
    }
    if (c == 0) out[tb + tok] = bestk;
  }
}

// ---------------------------------------------------------------------------
extern "C" void kernel_launch(void* const* d_in, const int* in_sizes, int n_in,
                              void* d_out, int out_size, void* d_ws,
                              size_t ws_size, hipStream_t stream) {
  const float* x = (const float*)d_in[0];    // (8,2048,512)
  const float* w = (const float*)d_in[1];    // (16,512)
  const float* cb = (const float*)d_in[2];   // (8192,16)

  f16* cbA = (f16*)d_ws;                        // 512 KB
  float* c2s = (float*)(cbA + (size_t)K * 32);  // 32 KB
  f16* wAf = (f16*)(c2s + K);                   // 32 KB

  prep<<<K / 64 + 1, 256, 0, stream>>>(cb, w, cbA, c2s, wAf);
  fused<<<NTOK / 64, 1024, 0, stream>>>(x, cb, cbA, c2s, wAf, (int*)d_out);
}